// Round 4
// baseline (156.375 us; speedup 1.0000x reference)
//
#include <hip/hip_runtime.h>
#include <math.h>

#define GRID_G 60
#define GRID_GG 3600

__device__ __forceinline__ int   f2i(float x){ return __float_as_int(x); }
__device__ __forceinline__ float i2f(int x){ return __int_as_float(x); }

// DPP lane-permute within rows of 16. 0xB1=quad_perm[1,0,3,2](xor1),
// 0x4E=quad_perm[2,3,0,1](xor2), 0x124=row_ror:4, 0x128=row_ror:8.
template<int CTRL>
__device__ __forceinline__ float dppmov(float v){
  return i2f(__builtin_amdgcn_update_dpp(0, f2i(v), CTRL, 0xF, 0xF, true));
}
// After xor1+xor2 every lane holds its quad's result; ror:4 then ror:8
// combine all four quads -> every lane of the 16-row holds the full result.
__device__ __forceinline__ float red16sum(float v){
  v += dppmov<0xB1>(v); v += dppmov<0x4E>(v);
  v += dppmov<0x124>(v); v += dppmov<0x128>(v);
  return v;
}
__device__ __forceinline__ float red16max(float v){
  v = fmaxf(v, dppmov<0xB1>(v));  v = fmaxf(v, dppmov<0x4E>(v));
  v = fmaxf(v, dppmov<0x124>(v)); v = fmaxf(v, dppmov<0x128>(v));
  return v;
}
__device__ __forceinline__ float red16min(float v){
  v = fminf(v, dppmov<0xB1>(v));  v = fminf(v, dppmov<0x4E>(v));
  v = fminf(v, dppmov<0x124>(v)); v = fminf(v, dppmov<0x128>(v));
  return v;
}
__device__ __forceinline__ float swz_xor16(float v){
  return i2f(__builtin_amdgcn_ds_swizzle(f2i(v), 0x401F));  // lane ^ 16
}
__device__ __forceinline__ float rdl(float v, int l){
  return i2f(__builtin_amdgcn_readlane(f2i(v), l));
}
__device__ __forceinline__ float bperm(int idxbytes, float v){
  return i2f(__builtin_amdgcn_ds_bpermute(idxbytes, f2i(v)));
}
__device__ __forceinline__ float frcp(float x){ return __builtin_amdgcn_rcpf(x); }
__device__ __forceinline__ float fsig(float x){ return frcp(1.0f + __expf(-x)); }
__device__ __forceinline__ float ftanh(float x){ return 1.0f - 2.0f*frcp(1.0f + __expf(2.0f*x)); }

// One 64-thread block = one wave = 4 boxes. No cross-wave dependencies.
// Weights lane-distributed (rows j=lane, lane+64); activations via small LDS
// (uniform-address b128 broadcast) produced and consumed by the SAME wave.
__global__ __launch_bounds__(64) void tracker_kernel(
    const float* __restrict__ mv,        // (2,60,60)
    const float* __restrict__ boxes,     // (N,4)
    const float* __restrict__ W_stats, const float* __restrict__ b_stats,
    const float* __restrict__ g_stats, const float* __restrict__ be_stats,
    const float* __restrict__ W_b1,  const float* __restrict__ b_b1,
    const float* __restrict__ g_b1,  const float* __restrict__ be_b1,
    const float* __restrict__ W_b2,  const float* __restrict__ b_b2,
    const float* __restrict__ g_b2,  const float* __restrict__ be_b2,
    const float* __restrict__ W_ih,  const float* __restrict__ b_ih,
    const float* __restrict__ b_hh,
    const float* __restrict__ W_p1,  const float* __restrict__ b_p1,
    const float* __restrict__ W_p2,  const float* __restrict__ b_p2,
    const float* __restrict__ W_s1,  const float* __restrict__ b_s1,
    const float* __restrict__ W_s2,  const float* __restrict__ b_s2,
    const float* __restrict__ W_c1,  const float* __restrict__ b_c1,
    const float* __restrict__ W_c2,  const float* __restrict__ b_c2,
    float* __restrict__ out, int N)
{
  __shared__ __align__(16) float x_lds[4][104];   // 96 used; 104 de-skews write banks
  __shared__ __align__(16) float h_lds[4][128];

  const int lane = threadIdx.x;        // 0..63
  const int grp  = lane >> 4;          // box slot 0..3 (phase 1 only)
  const int l16  = lane & 15;
  const int base = blockIdx.x * 4;

  // ========== Phase 1: motion stats + small MLPs (16 lanes per box) ==========
  {
    int gb = base + grp; if (gb >= N) gb = N - 1;    // tail: duplicate work, writes guarded
    const float4 bx = ((const float4*)boxes)[gb];
    const float bn0 = fminf(fmaxf(bx.x * (1.0f/960.0f), 0.f), 1.f);
    const float bn1 = fminf(fmaxf(bx.y * (1.0f/960.0f), 0.f), 1.f);
    const float bn2 = fminf(fmaxf(bx.z * (1.0f/960.0f), 0.f), 1.f);
    const float bn3 = fminf(fmaxf(bx.w * (1.0f/960.0f), 0.f), 1.f);

    int x1 = (int)floorf(bn0 * 60.f); x1 = min(max(x1, 0), 59);
    int y1 = (int)floorf(bn1 * 60.f); y1 = min(max(y1, 0), 59);
    int x2 = (int)ceilf (bn2 * 60.f); x2 = min(max(x2, x1 + 1), 60);
    int y2 = (int)ceilf (bn3 * 60.f); y2 = min(max(y2, y1 + 1), 60);
    const int w = x2 - x1, hh = y2 - y1;
    const int cnt = w * hh;                         // <= ~121
    const float rw = 1.0f / (float)w;

    float s0=0.f, s1=0.f, q0=0.f, q1=0.f;
    float hi0=-1e30f, hi1=-1e30f, lo0=1e30f, lo1=1e30f;
    for (int c = l16; c < cnt; c += 16) {
      // yy = c/w via float: (c+0.5)*rcp(w); margin 0.5/w >> fp32 ulp at c<=121
      const int yy = (int)(((float)c + 0.5f) * rw);
      const int xx = c - yy * w;
      const int idx = (y1 + yy) * GRID_G + (x1 + xx);
      const float m0 = mv[idx];
      const float m1 = mv[GRID_GG + idx];
      s0 += m0; q0 += m0*m0; hi0 = fmaxf(hi0, m0); lo0 = fminf(lo0, m0);
      s1 += m1; q1 += m1*m1; hi1 = fmaxf(hi1, m1); lo1 = fminf(lo1, m1);
    }
    s0 = red16sum(s0); q0 = red16sum(q0); hi0 = red16max(hi0); lo0 = red16min(lo0);
    s1 = red16sum(s1); q1 = red16sum(q1); hi1 = red16max(hi1); lo1 = red16min(lo1);
    const float inv = frcp((float)cnt);
    float st[6];
    st[0] = s0 * inv;
    st[1] = s1 * inv;
    st[2] = sqrtf(fmaxf(q0 * inv - st[0]*st[0], 0.f));
    st[3] = sqrtf(fmaxf(q1 * inv - st[1]*st[1], 0.f));
    st[4] = hi0 - lo0;
    st[5] = hi1 - lo1;

    // mv_feat: lane covers rows l16+16m (m=0..3); LN over 64; relu -> x_lds[grp][0..63]
    {
      float vm[4], vsum = 0.f, vsq = 0.f;
      #pragma unroll
      for (int m = 0; m < 4; ++m) {
        const int row = l16 + 16*m;
        const float* Wr = W_stats + row * 6;
        float v = b_stats[row];
        #pragma unroll
        for (int k = 0; k < 6; ++k) v = fmaf(st[k], Wr[k], v);
        vm[m] = v; vsum += v; vsq = fmaf(v, v, vsq);
      }
      const float mu  = red16sum(vsum) * (1.0f/64.0f);
      const float var = red16sum(vsq)  * (1.0f/64.0f) - mu*mu;
      const float rs  = rsqrtf(var + 1e-5f);
      #pragma unroll
      for (int m = 0; m < 4; ++m) {
        const int row = l16 + 16*m;
        x_lds[grp][row] = fmaxf((vm[m]-mu)*rs*g_stats[row] + be_stats[row], 0.f);
      }
    }

    // h1: rows l16, l16+16; LN over 32 (2 values/lane over 16 lanes)
    float h1a, h1b;
    {
      const float* Wa = W_b1 + l16 * 4;
      const float* Wb = W_b1 + (l16 + 16) * 4;
      const float v0 = b_b1[l16]    + bn0*Wa[0] + bn1*Wa[1] + bn2*Wa[2] + bn3*Wa[3];
      const float v1 = b_b1[l16+16] + bn0*Wb[0] + bn1*Wb[1] + bn2*Wb[2] + bn3*Wb[3];
      const float mu  = red16sum(v0 + v1) * (1.0f/32.0f);
      const float var = red16sum(v0*v0 + v1*v1) * (1.0f/32.0f) - mu*mu;
      const float rs  = rsqrtf(var + 1e-5f);
      h1a = fmaxf((v0-mu)*rs*g_b1[l16]    + be_b1[l16],    0.f);
      h1b = fmaxf((v1-mu)*rs*g_b1[l16+16] + be_b1[l16+16], 0.f);
    }

    // box_feat: rows l16, l16+16; h1 gathered via ds_bpermute within own 16-group
    {
      const int gbyte = (lane & 48) << 2;    // group base lane * 4 bytes
      const float* Wa = W_b2 + l16 * 32;
      const float* Wb = W_b2 + (l16 + 16) * 32;
      float u0 = b_b2[l16], u1 = b_b2[l16+16];
      #pragma unroll
      for (int k = 0; k < 16; ++k) {
        const float hk = bperm(gbyte + (k << 2), h1a);
        u0 = fmaf(Wa[k], hk, u0); u1 = fmaf(Wb[k], hk, u1);
      }
      #pragma unroll
      for (int k = 0; k < 16; ++k) {
        const float hk = bperm(gbyte + (k << 2), h1b);
        u0 = fmaf(Wa[16+k], hk, u0); u1 = fmaf(Wb[16+k], hk, u1);
      }
      const float mu  = red16sum(u0 + u1) * (1.0f/32.0f);
      const float var = red16sum(u0*u0 + u1*u1) * (1.0f/32.0f) - mu*mu;
      const float rs  = rsqrtf(var + 1e-5f);
      x_lds[grp][64 + l16] = fmaxf((u0-mu)*rs*g_b2[l16]    + be_b2[l16],    0.f);
      x_lds[grp][80 + l16] = fmaxf((u1-mu)*rs*g_b2[l16+16] + be_b2[l16+16], 0.f);
    }
  }
  __syncthreads();   // single-wave block: compiles to a cheap waitcnt(+barrier)

  // ========== Phase 2: LSTM gates. Lane holds rows j=lane, j+64 for i,g,o ======
  // (h0=c0=0 => W_hh and the f-gate drop out entirely)
  float hA[4], hB[4];   // h[box][j=lane], h[box][j=lane+64]
  {
    const float4* Wi0 = (const float4*)(W_ih + (size_t)(lane      ) * 96);
    const float4* Wi1 = (const float4*)(W_ih + (size_t)(lane +  64) * 96);
    const float4* Wg0 = (const float4*)(W_ih + (size_t)(lane + 256) * 96);
    const float4* Wg1 = (const float4*)(W_ih + (size_t)(lane + 320) * 96);
    const float4* Wo0 = (const float4*)(W_ih + (size_t)(lane + 384) * 96);
    const float4* Wo1 = (const float4*)(W_ih + (size_t)(lane + 448) * 96);
    float aI0[4]={0,0,0,0}, aI1[4]={0,0,0,0};
    float aG0[4]={0,0,0,0}, aG1[4]={0,0,0,0};
    float aO0[4]={0,0,0,0}, aO1[4]={0,0,0,0};
    #pragma unroll 2
    for (int kk = 0; kk < 24; ++kk) {
      const float4 wi0 = Wi0[kk], wi1 = Wi1[kk];
      const float4 wg0 = Wg0[kk], wg1 = Wg1[kk];
      const float4 wo0 = Wo0[kk], wo1 = Wo1[kk];
      float4 xv[4];
      #pragma unroll
      for (int b = 0; b < 4; ++b) xv[b] = *(const float4*)(&x_lds[b][kk*4]);
      #pragma unroll
      for (int b = 0; b < 4; ++b) {
        const float4 x4 = xv[b];
        aI0[b] = fmaf(wi0.x,x4.x, fmaf(wi0.y,x4.y, fmaf(wi0.z,x4.z, fmaf(wi0.w,x4.w, aI0[b]))));
        aI1[b] = fmaf(wi1.x,x4.x, fmaf(wi1.y,x4.y, fmaf(wi1.z,x4.z, fmaf(wi1.w,x4.w, aI1[b]))));
        aG0[b] = fmaf(wg0.x,x4.x, fmaf(wg0.y,x4.y, fmaf(wg0.z,x4.z, fmaf(wg0.w,x4.w, aG0[b]))));
        aG1[b] = fmaf(wg1.x,x4.x, fmaf(wg1.y,x4.y, fmaf(wg1.z,x4.z, fmaf(wg1.w,x4.w, aG1[b]))));
        aO0[b] = fmaf(wo0.x,x4.x, fmaf(wo0.y,x4.y, fmaf(wo0.z,x4.z, fmaf(wo0.w,x4.w, aO0[b]))));
        aO1[b] = fmaf(wo1.x,x4.x, fmaf(wo1.y,x4.y, fmaf(wo1.z,x4.z, fmaf(wo1.w,x4.w, aO1[b]))));
      }
    }
    const float bI0 = b_ih[lane      ] + b_hh[lane      ];
    const float bI1 = b_ih[lane +  64] + b_hh[lane +  64];
    const float bG0 = b_ih[lane + 256] + b_hh[lane + 256];
    const float bG1 = b_ih[lane + 320] + b_hh[lane + 320];
    const float bO0 = b_ih[lane + 384] + b_hh[lane + 384];
    const float bO1 = b_ih[lane + 448] + b_hh[lane + 448];
    #pragma unroll
    for (int b = 0; b < 4; ++b) {
      const float c0 = fsig(aI0[b]+bI0) * ftanh(aG0[b]+bG0);
      const float c1 = fsig(aI1[b]+bI1) * ftanh(aG1[b]+bG1);
      hA[b] = fsig(aO0[b]+bO0) * ftanh(c0);
      hB[b] = fsig(aO1[b]+bO1) * ftanh(c1);
    }
    #pragma unroll
    for (int b = 0; b < 4; ++b) {
      h_lds[b][lane]      = hA[b];
      h_lds[b][lane + 64] = hB[b];
    }
  }
  __syncthreads();

  // ========== Phase 3: head hidden layers. Lane = row (0..63) of all 3 heads ====
  float up[4], us[4], uc[4];
  {
    const float4* Wp = (const float4*)(W_p1 + (size_t)lane * 128);
    const float4* Ws = (const float4*)(W_s1 + (size_t)lane * 128);
    const float4* Wc = (const float4*)(W_c1 + (size_t)lane * 128);
    #pragma unroll
    for (int b = 0; b < 4; ++b) { up[b]=0.f; us[b]=0.f; uc[b]=0.f; }
    #pragma unroll 2
    for (int kk = 0; kk < 32; ++kk) {
      const float4 wp = Wp[kk], ws = Ws[kk], wc = Wc[kk];
      float4 hv[4];
      #pragma unroll
      for (int b = 0; b < 4; ++b) hv[b] = *(const float4*)(&h_lds[b][kk*4]);
      #pragma unroll
      for (int b = 0; b < 4; ++b) {
        const float4 h4 = hv[b];
        up[b] = fmaf(wp.x,h4.x, fmaf(wp.y,h4.y, fmaf(wp.z,h4.z, fmaf(wp.w,h4.w, up[b]))));
        us[b] = fmaf(ws.x,h4.x, fmaf(ws.y,h4.y, fmaf(ws.z,h4.z, fmaf(ws.w,h4.w, us[b]))));
        uc[b] = fmaf(wc.x,h4.x, fmaf(wc.y,h4.y, fmaf(wc.z,h4.z, fmaf(wc.w,h4.w, uc[b]))));
      }
    }
    const float bp = b_p1[lane], bs = b_s1[lane], bc = b_c1[lane];
    #pragma unroll
    for (int b = 0; b < 4; ++b) {
      up[b] = fmaxf(up[b] + bp, 0.f);
      us[b] = fmaxf(us[b] + bs, 0.f);
      uc[b] = fmaxf(uc[b] + bc, 0.f);
    }
  }

  // ========== Phase 4: head output layers — 20 wave reductions (DPP + 1 swizzle)
  float res[4][5];
  {
    const float w2p0 = W_p2[lane], w2p1 = W_p2[64 + lane];
    const float w2s0 = W_s2[lane], w2s1 = W_s2[64 + lane];
    const float w2c0 = W_c2[lane];
    const float bp0 = b_p2[0], bp1 = b_p2[1];
    const float bs0 = b_s2[0], bs1 = b_s2[1];
    const float bc0 = b_c2[0];
    #pragma unroll
    for (int b = 0; b < 4; ++b) {
      float pr0 = w2p0 * up[b];
      float pr1 = w2p1 * up[b];
      float pr2 = w2s0 * us[b];
      float pr3 = w2s1 * us[b];
      float pr4 = w2c0 * uc[b];
      float r0 = red16sum(pr0); r0 += swz_xor16(r0);
      float r1 = red16sum(pr1); r1 += swz_xor16(r1);
      float r2 = red16sum(pr2); r2 += swz_xor16(r2);
      float r3 = red16sum(pr3); r3 += swz_xor16(r3);
      float r4 = red16sum(pr4); r4 += swz_xor16(r4);
      res[b][0] = rdl(r0,0) + rdl(r0,32) + bp0;
      res[b][1] = rdl(r1,0) + rdl(r1,32) + bp1;
      res[b][2] = rdl(r2,0) + rdl(r2,32) + bs0;
      res[b][3] = rdl(r3,0) + rdl(r3,32) + bs1;
      res[b][4] = rdl(r4,0) + rdl(r4,32) + bc0;
    }
  }

  // ========== Phase 5: box decode + write (values uniform; lane-select store) ===
  {
    float val[4][5];
    #pragma unroll
    for (int b = 0; b < 4; ++b) {
      int gb2 = base + b; if (gb2 >= N) gb2 = N - 1;
      const float4 bb = ((const float4*)boxes)[gb2];
      const float cx = (bb.x + bb.z) * 0.5f;
      const float cy = (bb.y + bb.w) * 0.5f;
      const float w  = bb.z - bb.x;
      const float hh = bb.w - bb.y;
      const float ncx = cx + res[b][0];
      const float ncy = cy + res[b][1];
      const float nw  = w  * __expf(res[b][2]);
      const float nh  = hh * __expf(res[b][3]);
      val[b][0] = ncx - nw * 0.5f;
      val[b][1] = ncy - nh * 0.5f;
      val[b][2] = ncx + nw * 0.5f;
      val[b][3] = ncy + nh * 0.5f;
      val[b][4] = fsig(res[b][4]);
    }
    float ov = 0.f;
    #pragma unroll
    for (int b = 0; b < 4; ++b)
      #pragma unroll
      for (int o = 0; o < 5; ++o)
        ov = (lane == b*5 + o) ? val[b][o] : ov;
    if (lane < 20) {
      const int bxi = lane / 5;
      if (base + bxi < N) out[(size_t)base * 5 + lane] = ov;
    }
  }
}

extern "C" void kernel_launch(void* const* d_in, const int* in_sizes, int n_in,
                              void* d_out, int out_size, void* d_ws, size_t ws_size,
                              hipStream_t stream) {
  (void)n_in; (void)out_size; (void)d_ws; (void)ws_size;
  const float* mv       = (const float*)d_in[0];
  const float* boxes    = (const float*)d_in[1];
  const float* W_stats  = (const float*)d_in[2];
  const float* b_stats  = (const float*)d_in[3];
  const float* g_stats  = (const float*)d_in[4];
  const float* be_stats = (const float*)d_in[5];
  const float* W_b1     = (const float*)d_in[6];
  const float* b_b1     = (const float*)d_in[7];
  const float* g_b1     = (const float*)d_in[8];
  const float* be_b1    = (const float*)d_in[9];
  const float* W_b2     = (const float*)d_in[10];
  const float* b_b2     = (const float*)d_in[11];
  const float* g_b2     = (const float*)d_in[12];
  const float* be_b2    = (const float*)d_in[13];
  const float* W_ih     = (const float*)d_in[14];
  // d_in[15] = W_hh: unused (h0 == 0)
  const float* b_ih     = (const float*)d_in[16];
  const float* b_hh     = (const float*)d_in[17];
  const float* W_p1     = (const float*)d_in[18];
  const float* b_p1     = (const float*)d_in[19];
  const float* W_p2     = (const float*)d_in[20];
  const float* b_p2     = (const float*)d_in[21];
  const float* W_s1     = (const float*)d_in[22];
  const float* b_s1     = (const float*)d_in[23];
  const float* W_s2     = (const float*)d_in[24];
  const float* b_s2     = (const float*)d_in[25];
  const float* W_c1     = (const float*)d_in[26];
  const float* b_c1     = (const float*)d_in[27];
  const float* W_c2     = (const float*)d_in[28];
  const float* b_c2     = (const float*)d_in[29];

  const int N = in_sizes[1] / 4;
  const int grid = (N + 3) / 4;
  tracker_kernel<<<grid, 64, 0, stream>>>(
      mv, boxes,
      W_stats, b_stats, g_stats, be_stats,
      W_b1, b_b1, g_b1, be_b1,
      W_b2, b_b2, g_b2, be_b2,
      W_ih, b_ih, b_hh,
      W_p1, b_p1, W_p2, b_p2,
      W_s1, b_s1, W_s2, b_s2,
      W_c1, b_c1, W_c2, b_c2,
      (float*)d_out, N);
}

// Round 5
// 132.550 us; speedup vs baseline: 1.1797x; 1.1797x over previous
//
#include <hip/hip_runtime.h>
#include <math.h>

#define GRID_G 60
#define GRID_GG 3600
#define BPB 8

// ---------- width-32 butterfly reductions ----------
__device__ __forceinline__ float wred32sum(float v){
  #pragma unroll
  for (int m = 16; m; m >>= 1) v += __shfl_xor(v, m, 32);
  return v;
}
__device__ __forceinline__ float wred32max(float v){
  #pragma unroll
  for (int m = 16; m; m >>= 1) v = fmaxf(v, __shfl_xor(v, m, 32));
  return v;
}
__device__ __forceinline__ float wred32min(float v){
  #pragma unroll
  for (int m = 16; m; m >>= 1) v = fminf(v, __shfl_xor(v, m, 32));
  return v;
}
__device__ __forceinline__ float frcp(float x){ return __builtin_amdgcn_rcpf(x); }
__device__ __forceinline__ float fsig(float x){ return frcp(1.0f + __expf(-x)); }
__device__ __forceinline__ float ftanh(float x){ return 1.0f - 2.0f*frcp(1.0f + __expf(2.0f*x)); }

// ---------- kernel 1: weight transpose to K-major ----------
// wt_ih[k*384 + r'] = W_ih[row(r')*96 + k], row(r') = r'<128 ? r' : r'+128
//   (r' 0..127 = i-gate, 128..255 = g-gate, 256..383 = o-gate; f-gate dropped)
// wt_h[k*192 + r''] = {W_p1|W_s1|W_c1}[(r''&63)*128 + k]   (r'' 0..191)
__global__ __launch_bounds__(256) void transpose_kernel(
    const float* __restrict__ W_ih,
    const float* __restrict__ W_p1, const float* __restrict__ W_s1,
    const float* __restrict__ W_c1,
    float* __restrict__ wt_ih, float* __restrict__ wt_h)
{
  const int i = blockIdx.x * 256 + threadIdx.x;
  if (i < 96*384) {
    const int k = i / 384, r = i % 384;
    const int row = (r < 128) ? r : (r + 128);
    wt_ih[i] = W_ih[row * 96 + k];
  } else {
    const int j = i - 96*384;
    if (j < 128*192) {
      const int k = j / 192, r = j % 192;
      const float* W = (r < 64) ? W_p1 : (r < 128) ? W_s1 : W_c1;
      wt_h[j] = W[(r & 63) * 128 + k];
    }
  }
}

// ---------- kernel 2: fused tracker, coalesced GEMV phases ----------
__global__ __launch_bounds__(256) void tracker_kernel(
    const float* __restrict__ mv,        // (2,60,60)
    const float* __restrict__ boxes,     // (N,4)
    const float* __restrict__ W_stats, const float* __restrict__ b_stats,
    const float* __restrict__ g_stats, const float* __restrict__ be_stats,
    const float* __restrict__ W_b1,  const float* __restrict__ b_b1,
    const float* __restrict__ g_b1,  const float* __restrict__ be_b1,
    const float* __restrict__ W_b2,  const float* __restrict__ b_b2,
    const float* __restrict__ g_b2,  const float* __restrict__ be_b2,
    const float* __restrict__ wt_ih, // K-major [96][384]
    const float* __restrict__ b_ih,  const float* __restrict__ b_hh,
    const float* __restrict__ wt_h,  // K-major [128][192]
    const float* __restrict__ b_p1,  const float* __restrict__ W_p2, const float* __restrict__ b_p2,
    const float* __restrict__ b_s1,  const float* __restrict__ W_s2, const float* __restrict__ b_s2,
    const float* __restrict__ b_c1,  const float* __restrict__ W_c2, const float* __restrict__ b_c2,
    float* __restrict__ out, int N)
{
  __shared__ __align__(16) float x_lds[BPB][96];     // [mv_feat(64) | box_feat(32)]
  __shared__ __align__(16) float gates_lds[BPB][384];// i(128) g(128) o(128) pre-acts
  __shared__ __align__(16) float h_lds[BPB][128];    // LSTM hidden
  __shared__ __align__(16) float h1_lds[BPB][32];
  __shared__ float u_lds[3*BPB][65];                 // head hidden, +1 pad
  __shared__ float res_lds[BPB][5];

  const int tid  = threadIdx.x;
  const int base = blockIdx.x * BPB;

  // ========== Phase 1: one half-wave (32 lanes) per box, all 8 boxes parallel ==
  {
    const int b   = tid >> 5;
    const int l32 = tid & 31;
    int gb = base + b; if (gb >= N) gb = N - 1;
    const float4 bx = ((const float4*)boxes)[gb];
    const float bn0 = fminf(fmaxf(bx.x * (1.0f/960.0f), 0.f), 1.f);
    const float bn1 = fminf(fmaxf(bx.y * (1.0f/960.0f), 0.f), 1.f);
    const float bn2 = fminf(fmaxf(bx.z * (1.0f/960.0f), 0.f), 1.f);
    const float bn3 = fminf(fmaxf(bx.w * (1.0f/960.0f), 0.f), 1.f);

    int x1 = (int)floorf(bn0 * 60.f); x1 = min(max(x1, 0), 59);
    int y1 = (int)floorf(bn1 * 60.f); y1 = min(max(y1, 0), 59);
    int x2 = (int)ceilf (bn2 * 60.f); x2 = min(max(x2, x1 + 1), 60);
    int y2 = (int)ceilf (bn3 * 60.f); y2 = min(max(y2, y1 + 1), 60);
    const int w = x2 - x1, hh = y2 - y1;
    const int cnt = w * hh;              // <= ~121
    const float rw = 1.0f / (float)w;

    float s0=0.f, s1=0.f, q0=0.f, q1=0.f;
    float hi0=-1e30f, hi1=-1e30f, lo0=1e30f, lo1=1e30f;
    for (int c = l32; c < cnt; c += 32) {
      const int yy = (int)(((float)c + 0.5f) * rw);   // exact floor(c/w) here
      const int xx = c - yy * w;
      const int idx = (y1 + yy) * GRID_G + (x1 + xx);
      const float m0 = mv[idx];
      const float m1 = mv[GRID_GG + idx];
      s0 += m0; q0 += m0*m0; hi0 = fmaxf(hi0, m0); lo0 = fminf(lo0, m0);
      s1 += m1; q1 += m1*m1; hi1 = fmaxf(hi1, m1); lo1 = fminf(lo1, m1);
    }
    s0 = wred32sum(s0); q0 = wred32sum(q0); hi0 = wred32max(hi0); lo0 = wred32min(lo0);
    s1 = wred32sum(s1); q1 = wred32sum(q1); hi1 = wred32max(hi1); lo1 = wred32min(lo1);
    const float inv = frcp((float)cnt);
    float st[6];
    st[0] = s0 * inv;
    st[1] = s1 * inv;
    st[2] = sqrtf(fmaxf(q0 * inv - st[0]*st[0], 0.f));
    st[3] = sqrtf(fmaxf(q1 * inv - st[1]*st[1], 0.f));
    st[4] = hi0 - lo0;
    st[5] = hi1 - lo1;

    // mv_feat (64) + LN + relu
    {
      const float* Wr0 = W_stats + l32 * 6;
      const float* Wr1 = W_stats + (l32 + 32) * 6;
      float v0 = b_stats[l32], v1 = b_stats[l32 + 32];
      #pragma unroll
      for (int k = 0; k < 6; ++k) { v0 = fmaf(st[k], Wr0[k], v0); v1 = fmaf(st[k], Wr1[k], v1); }
      const float mu  = wred32sum(v0 + v1) * (1.0f/64.0f);
      const float var = wred32sum(v0*v0 + v1*v1) * (1.0f/64.0f) - mu*mu;
      const float rs  = rsqrtf(var + 1e-5f);
      x_lds[b][l32     ] = fmaxf((v0-mu)*rs*g_stats[l32     ] + be_stats[l32     ], 0.f);
      x_lds[b][l32 + 32] = fmaxf((v1-mu)*rs*g_stats[l32 + 32] + be_stats[l32 + 32], 0.f);
    }

    // h1 (32) + LN + relu
    {
      const float* Wr = W_b1 + l32 * 4;
      const float v = b_b1[l32] + bn0*Wr[0] + bn1*Wr[1] + bn2*Wr[2] + bn3*Wr[3];
      const float mu  = wred32sum(v)   * (1.0f/32.0f);
      const float var = wred32sum(v*v) * (1.0f/32.0f) - mu*mu;
      h1_lds[b][l32] = fmaxf((v - mu) * rsqrtf(var + 1e-5f) * g_b1[l32] + be_b1[l32], 0.f);
    }
    __threadfence_block();   // same half-wave produces and consumes h1

    // box_feat (32) + LN + relu
    {
      const float* Wr = W_b2 + l32 * 32;
      float v = b_b2[l32];
      #pragma unroll
      for (int kk = 0; kk < 8; ++kk) {
        const float4 hv = *(const float4*)(&h1_lds[b][kk * 4]);  // broadcast
        const float4 wv = *(const float4*)(&Wr[kk * 4]);
        v = fmaf(wv.x,hv.x, fmaf(wv.y,hv.y, fmaf(wv.z,hv.z, fmaf(wv.w,hv.w, v))));
      }
      const float mu  = wred32sum(v)   * (1.0f/32.0f);
      const float var = wred32sum(v*v) * (1.0f/32.0f) - mu*mu;
      x_lds[b][64 + l32] = fmaxf((v - mu) * rsqrtf(var + 1e-5f) * g_b2[l32] + be_b2[l32], 0.f);
    }
  }
  __syncthreads();

  // ========== Phase 2a: gate pre-activations, COALESCED K-major weights =======
  // thread t<192: quad g = t%96 (rows 4g..4g+3 of r'-space), s = t/96 (boxes 4s..4s+3)
  if (tid < 192) {
    const int g = (tid < 96) ? tid : tid - 96;
    const int s = (tid < 96) ? 0 : 1;
    const int bs = s * 4;
    float acc[4][4];
    #pragma unroll
    for (int b = 0; b < 4; ++b)
      #pragma unroll
      for (int j = 0; j < 4; ++j) acc[b][j] = 0.f;
    const float4* WT = (const float4*)wt_ih;   // [k][96 quads]
    #pragma unroll 2
    for (int k4 = 0; k4 < 24; ++k4) {
      float4 wv[4];
      #pragma unroll
      for (int kk = 0; kk < 4; ++kk) wv[kk] = WT[(size_t)(4*k4 + kk) * 96 + g];
      float4 xv[4];
      #pragma unroll
      for (int b = 0; b < 4; ++b) xv[b] = *(const float4*)(&x_lds[bs + b][k4 * 4]);
      #pragma unroll
      for (int b = 0; b < 4; ++b) {
        acc[b][0] = fmaf(wv[0].x, xv[b].x, fmaf(wv[1].x, xv[b].y, fmaf(wv[2].x, xv[b].z, fmaf(wv[3].x, xv[b].w, acc[b][0]))));
        acc[b][1] = fmaf(wv[0].y, xv[b].x, fmaf(wv[1].y, xv[b].y, fmaf(wv[2].y, xv[b].z, fmaf(wv[3].y, xv[b].w, acc[b][1]))));
        acc[b][2] = fmaf(wv[0].z, xv[b].x, fmaf(wv[1].z, xv[b].y, fmaf(wv[2].z, xv[b].z, fmaf(wv[3].z, xv[b].w, acc[b][2]))));
        acc[b][3] = fmaf(wv[0].w, xv[b].x, fmaf(wv[1].w, xv[b].y, fmaf(wv[2].w, xv[b].z, fmaf(wv[3].w, xv[b].w, acc[b][3]))));
      }
    }
    #pragma unroll
    for (int b = 0; b < 4; ++b)
      #pragma unroll
      for (int j = 0; j < 4; ++j)
        gates_lds[bs + b][4*g + j] = acc[b][j];
  }
  __syncthreads();

  // ========== Phase 2b: LSTM nonlinearity (h0=c0=0 => f-gate dropped) =========
  {
    const int j    = tid & 127;
    const int half = tid >> 7;
    const float bi = b_ih[j      ] + b_hh[j      ];
    const float bg = b_ih[j + 256] + b_hh[j + 256];
    const float bo = b_ih[j + 384] + b_hh[j + 384];
    #pragma unroll
    for (int bb = 0; bb < 4; ++bb) {
      const int b = half * 4 + bb;
      const float ai = gates_lds[b][j      ] + bi;
      const float ag = gates_lds[b][128 + j] + bg;
      const float ao = gates_lds[b][256 + j] + bo;
      const float c  = fsig(ai) * ftanh(ag);
      h_lds[b][j] = fsig(ao) * ftanh(c);
    }
  }
  __syncthreads();

  // ========== Phase 3: head hidden layers, COALESCED K-major weights ==========
  // thread t<192: quad g48 = t%48 (rows 4g48..4g48+3 of r''-space), s = t/48 (boxes 2s,2s+1)
  if (tid < 192) {
    const int s   = tid / 48;
    const int g48 = tid - s * 48;
    const int bs  = s * 2;
    float acc[2][4];
    #pragma unroll
    for (int b = 0; b < 2; ++b)
      #pragma unroll
      for (int j = 0; j < 4; ++j) acc[b][j] = 0.f;
    const float4* WT = (const float4*)wt_h;    // [k][48 quads]
    #pragma unroll 2
    for (int k4 = 0; k4 < 32; ++k4) {
      float4 wv[4];
      #pragma unroll
      for (int kk = 0; kk < 4; ++kk) wv[kk] = WT[(size_t)(4*k4 + kk) * 48 + g48];
      float4 hv[2];
      #pragma unroll
      for (int b = 0; b < 2; ++b) hv[b] = *(const float4*)(&h_lds[bs + b][k4 * 4]);
      #pragma unroll
      for (int b = 0; b < 2; ++b) {
        acc[b][0] = fmaf(wv[0].x, hv[b].x, fmaf(wv[1].x, hv[b].y, fmaf(wv[2].x, hv[b].z, fmaf(wv[3].x, hv[b].w, acc[b][0]))));
        acc[b][1] = fmaf(wv[0].y, hv[b].x, fmaf(wv[1].y, hv[b].y, fmaf(wv[2].y, hv[b].z, fmaf(wv[3].y, hv[b].w, acc[b][1]))));
        acc[b][2] = fmaf(wv[0].z, hv[b].x, fmaf(wv[1].z, hv[b].y, fmaf(wv[2].z, hv[b].z, fmaf(wv[3].z, hv[b].w, acc[b][2]))));
        acc[b][3] = fmaf(wv[0].w, hv[b].x, fmaf(wv[1].w, hv[b].y, fmaf(wv[2].w, hv[b].z, fmaf(wv[3].w, hv[b].w, acc[b][3]))));
      }
    }
    const int r0   = 4 * g48;          // rows r0..r0+3, all same head (g48 blocks of 16)
    const int head = r0 >> 6;
    const int brow = r0 & 63;
    const float* B1 = (head == 0) ? b_p1 : (head == 1) ? b_s1 : b_c1;
    #pragma unroll
    for (int j = 0; j < 4; ++j) {
      const float bias = B1[brow + j];
      #pragma unroll
      for (int b = 0; b < 2; ++b)
        u_lds[head * BPB + bs + b][brow + j] = fmaxf(acc[b][j] + bias, 0.f);
    }
  }
  __syncthreads();

  // ========== Phase 4: head output layers (8 boxes x 5 outputs = 40 threads) ==
  if (tid < BPB * 5) {
    const int b = tid / 5, o = tid % 5;
    const int head = (o < 2) ? 0 : (o < 4) ? 1 : 2;
    const float* W2; float bias;
    if      (o == 0) { W2 = W_p2;      bias = b_p2[0]; }
    else if (o == 1) { W2 = W_p2 + 64; bias = b_p2[1]; }
    else if (o == 2) { W2 = W_s2;      bias = b_s2[0]; }
    else if (o == 3) { W2 = W_s2 + 64; bias = b_s2[1]; }
    else             { W2 = W_c2;      bias = b_c2[0]; }
    const float* ur = u_lds[head * BPB + b];
    float a0 = bias, a1 = 0.f, a2 = 0.f, a3 = 0.f;
    #pragma unroll 4
    for (int k = 0; k < 64; k += 4) {
      a0 = fmaf(ur[k  ], W2[k  ], a0);
      a1 = fmaf(ur[k+1], W2[k+1], a1);
      a2 = fmaf(ur[k+2], W2[k+2], a2);
      a3 = fmaf(ur[k+3], W2[k+3], a3);
    }
    res_lds[b][o] = (a0 + a1) + (a2 + a3);
  }
  __syncthreads();

  // ========== Phase 5: box decode + write =====================================
  if (tid < BPB) {
    const int gb = base + tid;
    if (gb < N) {
      const float4 bx = ((const float4*)boxes)[gb];
      const float cx = (bx.x + bx.z) * 0.5f;
      const float cy = (bx.y + bx.w) * 0.5f;
      const float w  = bx.z - bx.x;
      const float hh = bx.w - bx.y;
      const float ncx = cx + res_lds[tid][0];
      const float ncy = cy + res_lds[tid][1];
      const float nw  = w  * __expf(res_lds[tid][2]);
      const float nh  = hh * __expf(res_lds[tid][3]);
      const float cf  = fsig(res_lds[tid][4]);
      float* op = out + (size_t)gb * 5;
      op[0] = ncx - nw * 0.5f;
      op[1] = ncy - nh * 0.5f;
      op[2] = ncx + nw * 0.5f;
      op[3] = ncy + nh * 0.5f;
      op[4] = cf;
    }
  }
}

extern "C" void kernel_launch(void* const* d_in, const int* in_sizes, int n_in,
                              void* d_out, int out_size, void* d_ws, size_t ws_size,
                              hipStream_t stream) {
  (void)n_in; (void)out_size; (void)ws_size;
  const float* mv       = (const float*)d_in[0];
  const float* boxes    = (const float*)d_in[1];
  const float* W_stats  = (const float*)d_in[2];
  const float* b_stats  = (const float*)d_in[3];
  const float* g_stats  = (const float*)d_in[4];
  const float* be_stats = (const float*)d_in[5];
  const float* W_b1     = (const float*)d_in[6];
  const float* b_b1     = (const float*)d_in[7];
  const float* g_b1     = (const float*)d_in[8];
  const float* be_b1    = (const float*)d_in[9];
  const float* W_b2     = (const float*)d_in[10];
  const float* b_b2     = (const float*)d_in[11];
  const float* g_b2     = (const float*)d_in[12];
  const float* be_b2    = (const float*)d_in[13];
  const float* W_ih     = (const float*)d_in[14];
  // d_in[15] = W_hh: unused (h0 == 0)
  const float* b_ih     = (const float*)d_in[16];
  const float* b_hh     = (const float*)d_in[17];
  const float* W_p1     = (const float*)d_in[18];
  const float* b_p1     = (const float*)d_in[19];
  const float* W_p2     = (const float*)d_in[20];
  const float* b_p2     = (const float*)d_in[21];
  const float* W_s1     = (const float*)d_in[22];
  const float* b_s1     = (const float*)d_in[23];
  const float* W_s2     = (const float*)d_in[24];
  const float* b_s2     = (const float*)d_in[25];
  const float* W_c1     = (const float*)d_in[26];
  const float* b_c1     = (const float*)d_in[27];
  const float* W_c2     = (const float*)d_in[28];
  const float* b_c2     = (const float*)d_in[29];

  float* wt_ih = (float*)d_ws;            // 96*384 floats
  float* wt_h  = wt_ih + 96 * 384;        // 128*192 floats  (total ~246 KB)

  transpose_kernel<<<240, 256, 0, stream>>>(W_ih, W_p1, W_s1, W_c1, wt_ih, wt_h);

  const int N = in_sizes[1] / 4;
  const int grid = (N + BPB - 1) / BPB;
  tracker_kernel<<<grid, 256, 0, stream>>>(
      mv, boxes,
      W_stats, b_stats, g_stats, be_stats,
      W_b1, b_b1, g_b1, be_b1,
      W_b2, b_b2, g_b2, be_b2,
      wt_ih, b_ih, b_hh,
      wt_h,
      b_p1, W_p2, b_p2,
      b_s1, W_s2, b_s2,
      b_c1, W_c2, b_c2,
      (float*)d_out, N);
}

// Round 6
// 131.460 us; speedup vs baseline: 1.1895x; 1.0083x over previous
//
#include <hip/hip_runtime.h>
#include <math.h>

#define GRID_G 60
#define GRID_GG 3600
#define BPB 8

// ---------- width-32 butterfly reductions ----------
__device__ __forceinline__ float wred32sum(float v){
  #pragma unroll
  for (int m = 16; m; m >>= 1) v += __shfl_xor(v, m, 32);
  return v;
}
__device__ __forceinline__ float wred32max(float v){
  #pragma unroll
  for (int m = 16; m; m >>= 1) v = fmaxf(v, __shfl_xor(v, m, 32));
  return v;
}
__device__ __forceinline__ float wred32min(float v){
  #pragma unroll
  for (int m = 16; m; m >>= 1) v = fminf(v, __shfl_xor(v, m, 32));
  return v;
}
__device__ __forceinline__ float frcp(float x){ return __builtin_amdgcn_rcpf(x); }
__device__ __forceinline__ float fsig(float x){ return frcp(1.0f + __expf(-x)); }
__device__ __forceinline__ float ftanh(float x){ return 1.0f - 2.0f*frcp(1.0f + __expf(2.0f*x)); }

// ---------- kernel 1: weight transpose to K-major (4 outputs/thread) ----------
// wt_ih[k*384 + r'] = W_ih[row(r')*96 + k], row(r') = r'<128 ? r' : r'+128
// wt_h [k*192 + r''] = {W_p1|W_s1|W_c1}[(r''&63)*128 + k]
__global__ __launch_bounds__(256) void transpose_kernel(
    const float* __restrict__ W_ih,
    const float* __restrict__ W_p1, const float* __restrict__ W_s1,
    const float* __restrict__ W_c1,
    float* __restrict__ wt_ih, float* __restrict__ wt_h)
{
  const int i4 = blockIdx.x * 256 + threadIdx.x;
  if (i4 < 9216) {                       // 96*384/4 quads
    const int e = i4 * 4;
    const int k = e / 384, r0 = e % 384;
    float4 v;
    {
      const int r = r0;     const int row = (r < 128) ? r : r + 128; v.x = W_ih[row*96 + k];
    }
    { const int r = r0 + 1; const int row = (r < 128) ? r : r + 128; v.y = W_ih[row*96 + k]; }
    { const int r = r0 + 2; const int row = (r < 128) ? r : r + 128; v.z = W_ih[row*96 + k]; }
    { const int r = r0 + 3; const int row = (r < 128) ? r : r + 128; v.w = W_ih[row*96 + k]; }
    ((float4*)wt_ih)[i4] = v;            // e == k*384 + r0
  } else if (i4 < 9216 + 6144) {         // 128*192/4 quads
    const int j4 = i4 - 9216;
    const int e = j4 * 4;
    const int k = e / 192, r0 = e % 192;
    const float* W = (r0 < 64) ? W_p1 : (r0 < 128) ? W_s1 : W_c1;
    float4 v;
    v.x = W[((r0    ) & 63) * 128 + k];
    v.y = W[((r0 + 1) & 63) * 128 + k];
    v.z = W[((r0 + 2) & 63) * 128 + k];
    v.w = W[((r0 + 3) & 63) * 128 + k];
    ((float4*)wt_h)[j4] = v;
  }
}

// ---------- kernel 2: fused tracker; K-split GEMV => each weight read ONCE/block
__global__ __launch_bounds__(256) void tracker_kernel(
    const float* __restrict__ mv,        // (2,60,60)
    const float* __restrict__ boxes,     // (N,4)
    const float* __restrict__ W_stats, const float* __restrict__ b_stats,
    const float* __restrict__ g_stats, const float* __restrict__ be_stats,
    const float* __restrict__ W_b1,  const float* __restrict__ b_b1,
    const float* __restrict__ g_b1,  const float* __restrict__ be_b1,
    const float* __restrict__ W_b2,  const float* __restrict__ b_b2,
    const float* __restrict__ g_b2,  const float* __restrict__ be_b2,
    const float* __restrict__ wt_ih, // K-major [96][384]
    const float* __restrict__ b_ih,  const float* __restrict__ b_hh,
    const float* __restrict__ wt_h,  // K-major [128][192]
    const float* __restrict__ b_p1,  const float* __restrict__ W_p2, const float* __restrict__ b_p2,
    const float* __restrict__ b_s1,  const float* __restrict__ W_s2, const float* __restrict__ b_s2,
    const float* __restrict__ b_c1,  const float* __restrict__ W_c2, const float* __restrict__ b_c2,
    float* __restrict__ out, int N)
{
  __shared__ __align__(16) float x_lds[BPB][96];   // [mv_feat(64) | box_feat(32)]
  __shared__ __align__(16) float sA[BPB][384];     // P2a partial (k-half 0) / P3 partials 0,1
  __shared__ __align__(16) float sB[BPB][384];     // P2a partial (k-half 1) / P3 partials 2,3
  __shared__ __align__(16) float h_lds[BPB][128];  // LSTM hidden
  __shared__ __align__(16) float h1_lds[BPB][32];
  __shared__ float u_lds[3*BPB][65];               // head hidden, +1 pad
  __shared__ float res_lds[BPB][5];

  const int tid  = threadIdx.x;
  const int base = blockIdx.x * BPB;

  // ========== Phase 1: one half-wave (32 lanes) per box, all 8 boxes parallel ==
  {
    const int b   = tid >> 5;
    const int l32 = tid & 31;
    int gb = base + b; if (gb >= N) gb = N - 1;
    const float4 bx = ((const float4*)boxes)[gb];
    const float bn0 = fminf(fmaxf(bx.x * (1.0f/960.0f), 0.f), 1.f);
    const float bn1 = fminf(fmaxf(bx.y * (1.0f/960.0f), 0.f), 1.f);
    const float bn2 = fminf(fmaxf(bx.z * (1.0f/960.0f), 0.f), 1.f);
    const float bn3 = fminf(fmaxf(bx.w * (1.0f/960.0f), 0.f), 1.f);

    int x1 = (int)floorf(bn0 * 60.f); x1 = min(max(x1, 0), 59);
    int y1 = (int)floorf(bn1 * 60.f); y1 = min(max(y1, 0), 59);
    int x2 = (int)ceilf (bn2 * 60.f); x2 = min(max(x2, x1 + 1), 60);
    int y2 = (int)ceilf (bn3 * 60.f); y2 = min(max(y2, y1 + 1), 60);
    const int w = x2 - x1, hh = y2 - y1;
    const int cnt = w * hh;              // <= ~121
    const float rw = 1.0f / (float)w;

    float s0=0.f, s1=0.f, q0=0.f, q1=0.f;
    float hi0=-1e30f, hi1=-1e30f, lo0=1e30f, lo1=1e30f;
    for (int c = l32; c < cnt; c += 32) {
      const int yy = (int)(((float)c + 0.5f) * rw);   // exact floor(c/w) here
      const int xx = c - yy * w;
      const int idx = (y1 + yy) * GRID_G + (x1 + xx);
      const float m0 = mv[idx];
      const float m1 = mv[GRID_GG + idx];
      s0 += m0; q0 += m0*m0; hi0 = fmaxf(hi0, m0); lo0 = fminf(lo0, m0);
      s1 += m1; q1 += m1*m1; hi1 = fmaxf(hi1, m1); lo1 = fminf(lo1, m1);
    }
    s0 = wred32sum(s0); q0 = wred32sum(q0); hi0 = wred32max(hi0); lo0 = wred32min(lo0);
    s1 = wred32sum(s1); q1 = wred32sum(q1); hi1 = wred32max(hi1); lo1 = wred32min(lo1);
    const float inv = frcp((float)cnt);
    float st[6];
    st[0] = s0 * inv;
    st[1] = s1 * inv;
    st[2] = sqrtf(fmaxf(q0 * inv - st[0]*st[0], 0.f));
    st[3] = sqrtf(fmaxf(q1 * inv - st[1]*st[1], 0.f));
    st[4] = hi0 - lo0;
    st[5] = hi1 - lo1;

    // mv_feat (64) + LN + relu
    {
      const float* Wr0 = W_stats + l32 * 6;
      const float* Wr1 = W_stats + (l32 + 32) * 6;
      float v0 = b_stats[l32], v1 = b_stats[l32 + 32];
      #pragma unroll
      for (int k = 0; k < 6; ++k) { v0 = fmaf(st[k], Wr0[k], v0); v1 = fmaf(st[k], Wr1[k], v1); }
      const float mu  = wred32sum(v0 + v1) * (1.0f/64.0f);
      const float var = wred32sum(v0*v0 + v1*v1) * (1.0f/64.0f) - mu*mu;
      const float rs  = rsqrtf(var + 1e-5f);
      x_lds[b][l32     ] = fmaxf((v0-mu)*rs*g_stats[l32     ] + be_stats[l32     ], 0.f);
      x_lds[b][l32 + 32] = fmaxf((v1-mu)*rs*g_stats[l32 + 32] + be_stats[l32 + 32], 0.f);
    }

    // h1 (32) + LN + relu
    {
      const float* Wr = W_b1 + l32 * 4;
      const float v = b_b1[l32] + bn0*Wr[0] + bn1*Wr[1] + bn2*Wr[2] + bn3*Wr[3];
      const float mu  = wred32sum(v)   * (1.0f/32.0f);
      const float var = wred32sum(v*v) * (1.0f/32.0f) - mu*mu;
      h1_lds[b][l32] = fmaxf((v - mu) * rsqrtf(var + 1e-5f) * g_b1[l32] + be_b1[l32], 0.f);
    }
    __threadfence_block();   // same half-wave produces and consumes h1

    // box_feat (32) + LN + relu
    {
      const float* Wr = W_b2 + l32 * 32;
      float v = b_b2[l32];
      #pragma unroll
      for (int kk = 0; kk < 8; ++kk) {
        const float4 hv = *(const float4*)(&h1_lds[b][kk * 4]);  // broadcast
        const float4 wv = *(const float4*)(&Wr[kk * 4]);
        v = fmaf(wv.x,hv.x, fmaf(wv.y,hv.y, fmaf(wv.z,hv.z, fmaf(wv.w,hv.w, v))));
      }
      const float mu  = wred32sum(v)   * (1.0f/32.0f);
      const float var = wred32sum(v*v) * (1.0f/32.0f) - mu*mu;
      x_lds[b][64 + l32] = fmaxf((v - mu) * rsqrtf(var + 1e-5f) * g_b2[l32] + be_b2[l32], 0.f);
    }
  }
  __syncthreads();

  // ========== Phase 2a: gate pre-acts, K-SPLIT. Thread = (row-quad q, k-half s)
  // Each weight element is read by exactly ONE thread => wt_ih streamed once/block.
  if (tid < 192) {
    const int q = (tid < 96) ? tid : tid - 96;   // rows 4q..4q+3 (r'-space)
    const int s = (tid < 96) ? 0 : 1;            // k-half: k in [48s, 48s+48)
    float acc[4][BPB];
    #pragma unroll
    for (int j = 0; j < 4; ++j)
      #pragma unroll
      for (int b = 0; b < BPB; ++b) acc[j][b] = 0.f;
    const float4* WT = (const float4*)wt_ih;     // [k][96 quads]
    const int k0 = s * 48;
    #pragma unroll 2
    for (int k4 = 0; k4 < 12; ++k4) {
      const int kb = k0 + 4*k4;
      const float4 wv0 = WT[(size_t)(kb    ) * 96 + q];
      const float4 wv1 = WT[(size_t)(kb + 1) * 96 + q];
      const float4 wv2 = WT[(size_t)(kb + 2) * 96 + q];
      const float4 wv3 = WT[(size_t)(kb + 3) * 96 + q];
      #pragma unroll
      for (int b = 0; b < BPB; ++b) {
        const float4 xv = *(const float4*)(&x_lds[b][kb]);   // uniform addr: broadcast
        acc[0][b] = fmaf(wv0.x, xv.x, fmaf(wv1.x, xv.y, fmaf(wv2.x, xv.z, fmaf(wv3.x, xv.w, acc[0][b]))));
        acc[1][b] = fmaf(wv0.y, xv.x, fmaf(wv1.y, xv.y, fmaf(wv2.y, xv.z, fmaf(wv3.y, xv.w, acc[1][b]))));
        acc[2][b] = fmaf(wv0.z, xv.x, fmaf(wv1.z, xv.y, fmaf(wv2.z, xv.z, fmaf(wv3.z, xv.w, acc[2][b]))));
        acc[3][b] = fmaf(wv0.w, xv.x, fmaf(wv1.w, xv.y, fmaf(wv2.w, xv.z, fmaf(wv3.w, xv.w, acc[3][b]))));
      }
    }
    float* dst = (s == 0) ? &sA[0][0] : &sB[0][0];
    #pragma unroll
    for (int b = 0; b < BPB; ++b) {
      float4 v; v.x = acc[0][b]; v.y = acc[1][b]; v.z = acc[2][b]; v.w = acc[3][b];
      *(float4*)(dst + b * 384 + 4 * q) = v;
    }
  }
  __syncthreads();

  // ========== Phase 2b: combine k-halves + LSTM nonlinearity (f-gate dropped) ==
  {
    const int j    = tid & 127;
    const int half = tid >> 7;
    const float bi = b_ih[j      ] + b_hh[j      ];
    const float bg = b_ih[j + 256] + b_hh[j + 256];
    const float bo = b_ih[j + 384] + b_hh[j + 384];
    #pragma unroll
    for (int bb = 0; bb < 4; ++bb) {
      const int b = half * 4 + bb;
      const float ai = sA[b][j      ] + sB[b][j      ] + bi;
      const float ag = sA[b][128 + j] + sB[b][128 + j] + bg;
      const float ao = sA[b][256 + j] + sB[b][256 + j] + bo;
      const float c  = fsig(ai) * ftanh(ag);
      h_lds[b][j] = fsig(ao) * ftanh(c);
    }
  }
  __syncthreads();   // h ready; sA/sB free for reuse

  // ========== Phase 3: head hidden, K-SPLIT x4. Thread = (row-quad q48, k-qtr s4)
  // wt_h streamed once/block. Partials: s4 0,1 -> sA[b][{0,192}+r], 2,3 -> sB.
  if (tid < 192) {
    const int q48 = tid % 48;            // rows 4q48..4q48+3 (r''-space, 192 rows)
    const int s4  = tid / 48;            // k-quarter: k in [32*s4, 32*s4+32)
    float acc[4][BPB];
    #pragma unroll
    for (int j = 0; j < 4; ++j)
      #pragma unroll
      for (int b = 0; b < BPB; ++b) acc[j][b] = 0.f;
    const float4* WT = (const float4*)wt_h;      // [k][48 quads]
    const int k0 = s4 * 32;
    #pragma unroll 2
    for (int k4 = 0; k4 < 8; ++k4) {
      const int kb = k0 + 4*k4;
      const float4 wv0 = WT[(size_t)(kb    ) * 48 + q48];
      const float4 wv1 = WT[(size_t)(kb + 1) * 48 + q48];
      const float4 wv2 = WT[(size_t)(kb + 2) * 48 + q48];
      const float4 wv3 = WT[(size_t)(kb + 3) * 48 + q48];
      #pragma unroll
      for (int b = 0; b < BPB; ++b) {
        const float4 hv = *(const float4*)(&h_lds[b][kb]);   // uniform addr: broadcast
        acc[0][b] = fmaf(wv0.x, hv.x, fmaf(wv1.x, hv.y, fmaf(wv2.x, hv.z, fmaf(wv3.x, hv.w, acc[0][b]))));
        acc[1][b] = fmaf(wv0.y, hv.x, fmaf(wv1.y, hv.y, fmaf(wv2.y, hv.z, fmaf(wv3.y, hv.w, acc[1][b]))));
        acc[2][b] = fmaf(wv0.z, hv.x, fmaf(wv1.z, hv.y, fmaf(wv2.z, hv.z, fmaf(wv3.z, hv.w, acc[2][b]))));
        acc[3][b] = fmaf(wv0.w, hv.x, fmaf(wv1.w, hv.y, fmaf(wv2.w, hv.z, fmaf(wv3.w, hv.w, acc[3][b]))));
      }
    }
    float* dst = (s4 < 2) ? &sA[0][0] : &sB[0][0];
    const int off = (s4 & 1) * 192;
    #pragma unroll
    for (int b = 0; b < BPB; ++b) {
      float4 v; v.x = acc[0][b]; v.y = acc[1][b]; v.z = acc[2][b]; v.w = acc[3][b];
      *(float4*)(dst + b * 384 + off + 4 * q48) = v;
    }
  }
  __syncthreads();

  // ========== Phase 3b: combine k-quarters + bias + relu -> u_lds ==============
  {
    #pragma unroll
    for (int i = 0; i < 6; ++i) {
      const int idx = tid + 256 * i;     // 1536 = 8 boxes x 192 rows
      const int b = idx / 192;
      const int r = idx - b * 192;
      const int head = r >> 6, brow = r & 63;
      const float bias = ((head == 0) ? b_p1 : (head == 1) ? b_s1 : b_c1)[brow];
      const float v = sA[b][r] + sA[b][192 + r] + sB[b][r] + sB[b][192 + r] + bias;
      u_lds[head * BPB + b][brow] = fmaxf(v, 0.f);
    }
  }
  __syncthreads();

  // ========== Phase 4: head output layers (8 boxes x 5 outputs = 40 threads) ==
  if (tid < BPB * 5) {
    const int b = tid / 5, o = tid % 5;
    const int head = (o < 2) ? 0 : (o < 4) ? 1 : 2;
    const float* W2; float bias;
    if      (o == 0) { W2 = W_p2;      bias = b_p2[0]; }
    else if (o == 1) { W2 = W_p2 + 64; bias = b_p2[1]; }
    else if (o == 2) { W2 = W_s2;      bias = b_s2[0]; }
    else if (o == 3) { W2 = W_s2 + 64; bias = b_s2[1]; }
    else             { W2 = W_c2;      bias = b_c2[0]; }
    const float* ur = u_lds[head * BPB + b];
    float a0 = bias, a1 = 0.f, a2 = 0.f, a3 = 0.f;
    #pragma unroll 4
    for (int k = 0; k < 64; k += 4) {
      a0 = fmaf(ur[k  ], W2[k  ], a0);
      a1 = fmaf(ur[k+1], W2[k+1], a1);
      a2 = fmaf(ur[k+2], W2[k+2], a2);
      a3 = fmaf(ur[k+3], W2[k+3], a3);
    }
    res_lds[b][o] = (a0 + a1) + (a2 + a3);
  }
  __syncthreads();

  // ========== Phase 5: box decode + write =====================================
  if (tid < BPB) {
    const int gb = base + tid;
    if (gb < N) {
      const float4 bx = ((const float4*)boxes)[gb];
      const float cx = (bx.x + bx.z) * 0.5f;
      const float cy = (bx.y + bx.w) * 0.5f;
      const float w  = bx.z - bx.x;
      const float hh = bx.w - bx.y;
      const float ncx = cx + res_lds[tid][0];
      const float ncy = cy + res_lds[tid][1];
      const float nw  = w  * __expf(res_lds[tid][2]);
      const float nh  = hh * __expf(res_lds[tid][3]);
      const float cf  = fsig(res_lds[tid][4]);
      float* op = out + (size_t)gb * 5;
      op[0] = ncx - nw * 0.5f;
      op[1] = ncy - nh * 0.5f;
      op[2] = ncx + nw * 0.5f;
      op[3] = ncy + nh * 0.5f;
      op[4] = cf;
    }
  }
}

extern "C" void kernel_launch(void* const* d_in, const int* in_sizes, int n_in,
                              void* d_out, int out_size, void* d_ws, size_t ws_size,
                              hipStream_t stream) {
  (void)n_in; (void)out_size; (void)ws_size;
  const float* mv       = (const float*)d_in[0];
  const float* boxes    = (const float*)d_in[1];
  const float* W_stats  = (const float*)d_in[2];
  const float* b_stats  = (const float*)d_in[3];
  const float* g_stats  = (const float*)d_in[4];
  const float* be_stats = (const float*)d_in[5];
  const float* W_b1     = (const float*)d_in[6];
  const float* b_b1     = (const float*)d_in[7];
  const float* g_b1     = (const float*)d_in[8];
  const float* be_b1    = (const float*)d_in[9];
  const float* W_b2     = (const float*)d_in[10];
  const float* b_b2     = (const float*)d_in[11];
  const float* g_b2     = (const float*)d_in[12];
  const float* be_b2    = (const float*)d_in[13];
  const float* W_ih     = (const float*)d_in[14];
  // d_in[15] = W_hh: unused (h0 == 0)
  const float* b_ih     = (const float*)d_in[16];
  const float* b_hh     = (const float*)d_in[17];
  const float* W_p1     = (const float*)d_in[18];
  const float* b_p1     = (const float*)d_in[19];
  const float* W_p2     = (const float*)d_in[20];
  const float* b_p2     = (const float*)d_in[21];
  const float* W_s1     = (const float*)d_in[22];
  const float* b_s1     = (const float*)d_in[23];
  const float* W_s2     = (const float*)d_in[24];
  const float* b_s2     = (const float*)d_in[25];
  const float* W_c1     = (const float*)d_in[26];
  const float* b_c1     = (const float*)d_in[27];
  const float* W_c2     = (const float*)d_in[28];
  const float* b_c2     = (const float*)d_in[29];

  float* wt_ih = (float*)d_ws;            // 96*384 floats
  float* wt_h  = wt_ih + 96 * 384;        // 128*192 floats (total ~246 KB)

  transpose_kernel<<<60, 256, 0, stream>>>(W_ih, W_p1, W_s1, W_c1, wt_ih, wt_h);

  const int N = in_sizes[1] / 4;
  const int grid = (N + BPB - 1) / BPB;
  tracker_kernel<<<grid, 256, 0, stream>>>(
      mv, boxes,
      W_stats, b_stats, g_stats, be_stats,
      W_b1, b_b1, g_b1, be_b1,
      W_b2, b_b2, g_b2, be_b2,
      wt_ih, b_ih, b_hh,
      wt_h,
      b_p1, W_p2, b_p2,
      b_s1, W_s2, b_s2,
      b_c1, W_c2, b_c2,
      (float*)d_out, N);
}